// Round 6
// baseline (928.793 us; speedup 1.0000x reference)
//
#include <hip/hip_runtime.h>

#define NF 64
#define NH 32
#define NK 16
#define NNODES 15
#define BLOCK 256
#define MBLOCK 512
#define MNWAVES (MBLOCK / 64)

// ---------------------------------------------------------------------------
// Level-synchronous design (round 6): one kernel per tree level, chained on
// the stream. Between levels, samples are bucketed into per-node id lists in
// the workspace (ballot histogram + 1 atomicAdd per wave per child). Every
// block is node-uniform by construction -> no in-block sort, no LDS, no
// __syncthreads: waves fully independent, TLP hides gather/weight latency
// (the monolithic kernel's 4-barriers-per-level lockstep was the dominant
// stall: VALUBusy 35% with per-SIMD VALU time only ~45us).
//
// Register rules carried from r1-r5:
//  * no runtime-indexed register arrays (r2: -> scratch)
//  * no fully-unrolled scalar-weight blocks (r3: SGPR window -> spill);
//    W2 rolled-g fused into logits (r4), W1 per-lane VMEM float4 with an
//    asm VGPR-pin on the node index to block scalar promotion.
// Per-sample FP accumulation order identical to r5 (absmax == 0).
// ---------------------------------------------------------------------------

__device__ __forceinline__ int node_bit(
    int id, int node,
    const float* __restrict__ x,
    const float* __restrict__ W1, const float* __restrict__ b1,
    const float* __restrict__ W2, const float* __restrict__ b2,
    const float* __restrict__ W3, const float* __restrict__ b3,
    const int* __restrict__ subset_idx)
{
    const int* si = subset_idx + node * NK;        // uniform -> s_load
    const float* xr = x + (size_t)id * NF;

    float xs[NK];
    #pragma unroll
    for (int k = 0; k < NK; ++k) xs[k] = xr[si[k]];

    // W1: per-lane float4 VMEM (L1 broadcast). Pin node in a VGPR so the
    // compiler cannot scalar-promote 128 in-flight s_loads (r3 spill mode).
    int vnode = node;
    asm volatile("" : "+v"(vnode));
    float h1v[NH];
    {
        const float4* w1g = (const float4*)(W1 + (size_t)vnode * (NH * NK));
        const float*  b1g = b1 + node * NH;
        #pragma unroll
        for (int j = 0; j < NH; ++j) {
            float acc = b1g[j];
            #pragma unroll
            for (int q = 0; q < NK / 4; ++q) {
                const float4 t = w1g[j * 4 + q];
                acc += t.x * xs[q * 4 + 0];
                acc += t.y * xs[q * 4 + 1];
                acc += t.z * xs[q * 4 + 2];
                acc += t.w * xs[q * 4 + 3];
            }
            h1v[j] = (acc >= 0.f) ? acc : 0.01f * acc;
        }
    }

    // h2 fused into logits: rolled g (runtime g touches MEMORY only, all
    // uniform -> SMEM pipe, bounded scalar window), k fully unrolled.
    const float* w2  = W2 + node * (NH * NH);
    const float* bb2 = b2 + node * NH;
    const float* w3  = W3 + node * 2 * NH;
    float l0 = b3[node * 2 + 0];
    float l1 = b3[node * 2 + 1];
    #pragma unroll 2
    for (int g = 0; g < NH; ++g) {
        float acc = bb2[g];
        #pragma unroll
        for (int k = 0; k < NH; ++k) acc += w2[g * NH + k] * h1v[k];
        const float h2 = (acc >= 0.f) ? acc : 0.01f * acc;
        l0 += w3[g]      * h2;
        l1 += w3[NH + g] * h2;
    }
    return (l0 < l1) ? 1 : 0;
}

// Per-wave two-bucket scatter: one atomicAdd per wave per child.
__device__ __forceinline__ void scatter_pair(
    int id, int valid, int bit, int c0, int c1, int N,
    int* __restrict__ cnt, int* __restrict__ dst)
{
    const int lane = threadIdx.x & 63;
    const unsigned long long lt = (lane == 0) ? 0ull : ((~0ull) >> (64 - lane));
    const unsigned long long vm = __ballot(valid != 0);
    const unsigned long long m1 = __ballot(valid && bit);
    const unsigned long long m0 = vm & ~m1;
    int b0 = 0, b1 = 0;
    if (lane == 0) {
        b0 = atomicAdd(&cnt[c0], __popcll(m0));
        b1 = atomicAdd(&cnt[c1], __popcll(m1));
    }
    b0 = __shfl(b0, 0);
    b1 = __shfl(b1, 0);
    if (valid) {
        const int  slot  = bit ? (b1 + __popcll(m1 & lt)) : (b0 + __popcll(m0 & lt));
        const int  child = bit ? c1 : c0;
        dst[(size_t)child * N + slot] = id;
    }
}

__global__ void k_level0(
    const float* __restrict__ x,
    const float* __restrict__ W1, const float* __restrict__ b1,
    const float* __restrict__ W2, const float* __restrict__ b2,
    const float* __restrict__ W3, const float* __restrict__ b3,
    const int* __restrict__ subset_idx,
    int* __restrict__ cnt1, int* __restrict__ dst, int N)
{
    int id = blockIdx.x * BLOCK + threadIdx.x;
    const int valid = (id < N) ? 1 : 0;
    if (!valid) id = 0;
    const int bit = node_bit(id, 0, x, W1, b1, W2, b2, W3, b3, subset_idx);
    scatter_pair(id, valid, bit, 0, 1, N, cnt1, dst);
}

__global__ void k_level_mid(
    const float* __restrict__ x,
    const float* __restrict__ W1, const float* __restrict__ b1,
    const float* __restrict__ W2, const float* __restrict__ b2,
    const float* __restrict__ W3, const float* __restrict__ b3,
    const int* __restrict__ subset_idx,
    const int* __restrict__ cntIn, const int* __restrict__ src,
    int* __restrict__ cntOut, int* __restrict__ dst,
    int N, int CH, int off)
{
    const int n = blockIdx.x / CH;      // node-local index at this level
    const int c = blockIdx.x % CH;
    const int cnt = cntIn[n];
    if (c * BLOCK >= cnt) return;       // block-uniform early exit
    const int i = c * BLOCK + (int)threadIdx.x;
    const int valid = (i < cnt) ? 1 : 0;
    const int id = src[(size_t)n * N + (valid ? i : 0)];
    const int bit = node_bit(id, off + n, x, W1, b1, W2, b2, W3, b3, subset_idx);
    scatter_pair(id, valid, bit, 2 * n, 2 * n + 1, N, cntOut, dst);
}

__global__ void k_level3(
    const float* __restrict__ x,
    const float* __restrict__ W1, const float* __restrict__ b1,
    const float* __restrict__ W2, const float* __restrict__ b2,
    const float* __restrict__ W3, const float* __restrict__ b3,
    const int* __restrict__ subset_idx,
    const int* __restrict__ cntIn, const int* __restrict__ src,
    const float* __restrict__ leaf_best, float* __restrict__ out,
    int N, int CH)
{
    const int n = blockIdx.x / CH;      // level-3 local loc (0..7)
    const int c = blockIdx.x % CH;
    const int cnt = cntIn[n];
    if (c * BLOCK >= cnt) return;
    const int i = c * BLOCK + (int)threadIdx.x;
    if (i >= cnt) return;               // no ballots below -> per-lane exit ok
    const int id = src[(size_t)n * N + i];
    const int bit = node_bit(id, 7 + n, x, W1, b1, W2, b2, W3, b3, subset_idx);
    out[id] = leaf_best[2 * n + bit];
}

// ---------------------------------------------------------------------------
// Fallback (r5 monolithic, 373us): used only if workspace is too small.
// ---------------------------------------------------------------------------
__global__ __attribute__((amdgpu_flat_work_group_size(MBLOCK, MBLOCK),
                          amdgpu_waves_per_eu(2, 4)))
void tree_mlp_mono(
    const float* __restrict__ x,
    const float* __restrict__ W1, const float* __restrict__ b1,
    const float* __restrict__ W2, const float* __restrict__ b2,
    const float* __restrict__ W3, const float* __restrict__ b3,
    const float* __restrict__ leaf_best, const int* __restrict__ subset_idx,
    float* __restrict__ out, int N)
{
    __shared__ __align__(16) float W2Lv[8 * 1024];
    __shared__ int      subL[NNODES * NK];
    __shared__ unsigned permL[MBLOCK];
    __shared__ int      sortL[64];

    const int tid  = threadIdx.x;
    const int lane = tid & 63;
    const int wv   = tid >> 6;

    for (int i = tid; i < NNODES * NK; i += MBLOCK) subL[i] = subset_idx[i];
    {
        const float4* srcp = (const float4*)W2;
        float4* dstp = (float4*)W2Lv;
        for (int i = tid; i < 256; i += MBLOCK) dstp[i] = srcp[i];
    }
    __syncthreads();

    const int s = blockIdx.x * MBLOCK + tid;
    int valid = (s < N) ? 1 : 0;
    int id    = valid ? s : 0;
    int loc = 0, off = 0;

    #pragma unroll 1
    for (int level = 0; level < 4; ++level) {
        if (level > 0) {
            const int nb = 1 << level;
            int myrank = 0;
            #pragma unroll 1
            for (int b = 0; b < nb; ++b) {
                const unsigned long long m = __ballot(loc == b);
                if (loc == b)
                    myrank = __popcll(m & ((1ull << lane) - 1ull));
                if (lane == 0)
                    sortL[b * MNWAVES + wv] = __popcll(m);
            }
            __syncthreads();
            {
                const int cnt4 = (1 << level) * 256;
                const float4* srcp = (const float4*)(W2 + (size_t)off * 1024);
                float4* dstp = (float4*)W2Lv;
                for (int i = tid; i < cnt4; i += MBLOCK) dstp[i] = srcp[i];
            }
            if (wv == 0) {
                const int cnt = nb * MNWAVES;
                int v = (lane < cnt) ? sortL[lane] : 0;
                int incl = v;
                #pragma unroll
                for (int d = 1; d < 64; d <<= 1) {
                    int t = __shfl_up(incl, d, 64);
                    if (lane >= d) incl += t;
                }
                if (lane < cnt) sortL[lane] = incl - v;
            }
            __syncthreads();
            const int slot = sortL[loc * MNWAVES + wv] + myrank;
            permL[slot] = ((unsigned)id << 5) | ((unsigned)valid << 4) | (unsigned)loc;
            __syncthreads();
            const unsigned p = permL[tid];
            id    = (int)(p >> 5);
            valid = (int)((p >> 4) & 1u);
            loc   = (int)(p & 15u);
            __syncthreads();
        }

        const int node = off + loc;
        const float* xr = x + (size_t)id * NF;

        float xs[NK];
        const int* si = subL + node * NK;
        #pragma unroll
        for (int k = 0; k < NK; ++k) xs[k] = xr[si[k]];

        float h1v[NH];
        {
            const float4* w1g = (const float4*)(W1 + node * (NH * NK));
            const float*  b1g = b1 + node * NH;
            #pragma unroll
            for (int j = 0; j < NH; ++j) {
                float acc = b1g[j];
                #pragma unroll
                for (int q = 0; q < NK / 4; ++q) {
                    const float4 t = w1g[j * 4 + q];
                    acc += t.x * xs[q * 4 + 0];
                    acc += t.y * xs[q * 4 + 1];
                    acc += t.z * xs[q * 4 + 2];
                    acc += t.w * xs[q * 4 + 3];
                }
                h1v[j] = (acc >= 0.f) ? acc : 0.01f * acc;
            }
        }

        const float* w2l = W2Lv + (loc << 10);
        const float* bb2 = b2 + node * NH;
        const float* w3g = W3 + node * 2 * NH;
        float l0 = b3[node * 2 + 0];
        float l1 = b3[node * 2 + 1];
        #pragma unroll 2
        for (int g = 0; g < NH; ++g) {
            float acc = bb2[g];
            const float4* row = (const float4*)(w2l + g * NH);
            #pragma unroll
            for (int q = 0; q < NH / 4; ++q) {
                const float4 t = row[q];
                acc += t.x * h1v[q * 4 + 0];
                acc += t.y * h1v[q * 4 + 1];
                acc += t.z * h1v[q * 4 + 2];
                acc += t.w * h1v[q * 4 + 3];
            }
            const float h2 = (acc >= 0.f) ? acc : 0.01f * acc;
            l0 += w3g[g]      * h2;
            l1 += w3g[NH + g] * h2;
        }

        const int bit = (l0 < l1) ? 1 : 0;
        loc = 2 * loc + bit;
        off = 2 * off + 1;
    }

    if (valid) out[id] = leaf_best[loc];
}

extern "C" void kernel_launch(void* const* d_in, const int* in_sizes, int n_in,
                              void* d_out, int out_size, void* d_ws, size_t ws_size,
                              hipStream_t stream) {
    const float* x         = (const float*)d_in[0];
    const float* W1        = (const float*)d_in[1];
    const float* b1        = (const float*)d_in[2];
    const float* W2        = (const float*)d_in[3];
    const float* b2        = (const float*)d_in[4];
    const float* W3        = (const float*)d_in[5];
    const float* b3        = (const float*)d_in[6];
    const float* leaf_best = (const float*)d_in[7];
    const int*   subset    = (const int*)d_in[8];

    const int N = in_sizes[0] / NF;

    // Workspace layout: [cnt: 14 ints, 256B-aligned region][bufA: 8N][bufB: 4N]
    const size_t need = 256 + (size_t)12 * (size_t)N * sizeof(int);
    if (ws_size >= need) {
        int* cnt  = (int*)d_ws;                       // cnt1=[0..1] cnt2=[2..5] cnt3=[6..13]
        int* bufA = (int*)((char*)d_ws + 256);
        int* bufB = bufA + (size_t)8 * N;
        hipMemsetAsync(cnt, 0, 64, stream);

        const int CH = (N + BLOCK - 1) / BLOCK;
        k_level0<<<CH, BLOCK, 0, stream>>>(
            x, W1, b1, W2, b2, W3, b3, subset, cnt + 0, bufA, N);
        k_level_mid<<<2 * CH, BLOCK, 0, stream>>>(
            x, W1, b1, W2, b2, W3, b3, subset, cnt + 0, bufA, cnt + 2, bufB, N, CH, 1);
        k_level_mid<<<4 * CH, BLOCK, 0, stream>>>(
            x, W1, b1, W2, b2, W3, b3, subset, cnt + 2, bufB, cnt + 6, bufA, N, CH, 3);
        k_level3<<<8 * CH, BLOCK, 0, stream>>>(
            x, W1, b1, W2, b2, W3, b3, subset, cnt + 6, bufA, leaf_best,
            (float*)d_out, N, CH);
    } else {
        const int grid = (N + MBLOCK - 1) / MBLOCK;
        tree_mlp_mono<<<grid, MBLOCK, 0, stream>>>(
            x, W1, b1, W2, b2, W3, b3, leaf_best, subset, (float*)d_out, N);
    }
}

// Round 7
// 633.983 us; speedup vs baseline: 1.4650x; 1.4650x over previous
//
#include <hip/hip_runtime.h>

#define NF 64
#define NH 32
#define NK 16
#define NNODES 15
#define BLOCK 512
#define NWAVES (BLOCK / 64)

// LDS: subL 960 + permL 2048 + sortL 256 = ~3.3 KB. No W2 staging.
//
// Evidence-driven design (r0-r6):
//  * r6 falsified "barriers are the stall": barrier-free node-uniform
//    k_level0 still ran VALUBusy 11%. The stall is memory latency vs
//    resident waves. So: shrink LDS to nothing and let 4 blocks/CU
//    (977-block grid) co-schedule.
//  * W2/b2/W3/b3 delivered like W1 has been since r0: per-lane VMEM
//    float4 with wave-(quasi)-uniform addresses -> L1 broadcast, 1-2
//    transactions/instr, pipelined by vmcnt scoreboard. No SMEM serial
//    chain (r4: 502us), no LDS staging (r5: 36KB -> occupancy cap).
//  * All weight bases derive from an asm-pinned VGPR node index so the
//    compiler cannot scalar-promote the fully-unrolled load set
//    (r3: SGPR-window blowup -> 170 MB scratch).
//  * No register array is ever runtime-indexed (r2: -> 500 MB scratch).
//  * FP accumulation order identical to r0/r5 (absmax must stay 0).

__global__ __attribute__((amdgpu_flat_work_group_size(BLOCK, BLOCK),
                          amdgpu_waves_per_eu(2, 4)))
void tree_mlp_kernel(
    const float* __restrict__ x,
    const float* __restrict__ W1, const float* __restrict__ b1,
    const float* __restrict__ W2, const float* __restrict__ b2,
    const float* __restrict__ W3, const float* __restrict__ b3,
    const float* __restrict__ leaf_best, const int* __restrict__ subset_idx,
    float* __restrict__ out, int N)
{
    __shared__ int      subL[NNODES * NK];     // 960 B
    __shared__ unsigned permL[BLOCK];          // 2048 B
    __shared__ int      sortL[64];             // nb*NWAVES <= 64

    const int tid  = threadIdx.x;
    const int lane = tid & 63;
    const int wv   = tid >> 6;

    for (int i = tid; i < NNODES * NK; i += BLOCK) subL[i] = subset_idx[i];
    __syncthreads();

    const int s = blockIdx.x * BLOCK + tid;
    int valid = (s < N) ? 1 : 0;
    int id    = valid ? s : 0;      // invalid lanes shadow sample 0 (stay live for ballots)
    int loc = 0, off = 0;

    #pragma unroll 1   // keep level loop rolled (I$)
    for (int level = 0; level < 4; ++level) {
        if (level > 0) {
            // ---- in-block counting sort by loc (nb buckets), ballot-based ----
            const int nb = 1 << level;
            int myrank = 0;
            #pragma unroll 1
            for (int b = 0; b < nb; ++b) {
                const unsigned long long m = __ballot(loc == b);
                if (loc == b)
                    myrank = __popcll(m & ((1ull << lane) - 1ull));
                if (lane == 0)
                    sortL[b * NWAVES + wv] = __popcll(m);
            }
            __syncthreads();

            // Wave-parallel exclusive scan over (bucket, wave) counts.
            if (wv == 0) {
                const int cnt = nb * NWAVES;                    // 16/32/64
                int v = (lane < cnt) ? sortL[lane] : 0;
                int incl = v;
                #pragma unroll
                for (int d = 1; d < 64; d <<= 1) {
                    int t = __shfl_up(incl, d, 64);
                    if (lane >= d) incl += t;
                }
                if (lane < cnt) sortL[lane] = incl - v;
            }
            __syncthreads();

            const int slot = sortL[loc * NWAVES + wv] + myrank;
            permL[slot] = ((unsigned)id << 5) | ((unsigned)valid << 4) | (unsigned)loc;
            __syncthreads();
            const unsigned p = permL[tid];
            id    = (int)(p >> 5);
            valid = (int)((p >> 4) & 1u);
            loc   = (int)(p & 15u);
            __syncthreads();           // protect permL/sortL reuse next level
        }

        const int node = off + loc;    // wave-(quasi)-uniform after sort

        // Pin the node index in a VGPR: every weight base below derives from
        // it, forcing per-lane VMEM (L1 broadcast) instead of scalar-promoted
        // s_load storms (r3 spill mode).
        int vnode = node;
        asm volatile("" : "+v"(vnode));

        const float* xr = x + (size_t)id * NF;

        // Per-lane subset gather (lane's OWN node); dies after h1.
        float xs[NK];
        const int* si = subL + node * NK;
        #pragma unroll
        for (int k = 0; k < NK; ++k) xs[k] = xr[si[k]];

        // h1 = leaky(W1[node] @ xs + b1) : per-lane float4 VMEM broadcast.
        float h1v[NH];
        {
            const float4* w1g = (const float4*)(W1 + (size_t)vnode * (NH * NK));
            const float*  b1g = b1 + (size_t)vnode * NH;
            #pragma unroll
            for (int j = 0; j < NH; ++j) {
                float acc = b1g[j];
                #pragma unroll
                for (int q = 0; q < NK / 4; ++q) {
                    const float4 t = w1g[j * 4 + q];
                    acc += t.x * xs[q * 4 + 0];
                    acc += t.y * xs[q * 4 + 1];
                    acc += t.z * xs[q * 4 + 2];
                    acc += t.w * xs[q * 4 + 3];
                }
                h1v[j] = (acc >= 0.f) ? acc : 0.01f * acc;
            }
        }

        // h2 fused into logits, fully unrolled, W2/b2/W3/b3 via the same
        // per-lane VMEM float4 broadcast path. Static indices everywhere.
        const float4* w2g = (const float4*)(W2 + (size_t)vnode * (NH * NH));
        const float*  bb2 = b2 + (size_t)vnode * NH;
        const float*  w3g = W3 + (size_t)vnode * 2 * NH;
        const float*  bb3 = b3 + (size_t)vnode * 2;
        float l0 = bb3[0];
        float l1 = bb3[1];

        #pragma unroll
        for (int g = 0; g < NH; ++g) {
            float acc = bb2[g];
            #pragma unroll
            for (int q = 0; q < NH / 4; ++q) {
                const float4 t = w2g[g * 8 + q];
                acc += t.x * h1v[q * 4 + 0];
                acc += t.y * h1v[q * 4 + 1];
                acc += t.z * h1v[q * 4 + 2];
                acc += t.w * h1v[q * 4 + 3];
            }
            const float h2 = (acc >= 0.f) ? acc : 0.01f * acc;
            l0 += w3g[g]      * h2;
            l1 += w3g[NH + g] * h2;
        }

        const int bit = (l0 < l1) ? 1 : 0;
        loc = 2 * loc + bit;
        off = 2 * off + 1;   // node offsets: 0, 1, 3, 7
    }

    if (valid) out[id] = leaf_best[loc];
}

extern "C" void kernel_launch(void* const* d_in, const int* in_sizes, int n_in,
                              void* d_out, int out_size, void* d_ws, size_t ws_size,
                              hipStream_t stream) {
    const float* x         = (const float*)d_in[0];
    const float* W1        = (const float*)d_in[1];
    const float* b1        = (const float*)d_in[2];
    const float* W2        = (const float*)d_in[3];
    const float* b2        = (const float*)d_in[4];
    const float* W3        = (const float*)d_in[5];
    const float* b3        = (const float*)d_in[6];
    const float* leaf_best = (const float*)d_in[7];
    const int*   subset    = (const int*)d_in[8];

    const int N = in_sizes[0] / NF;
    const int grid = (N + BLOCK - 1) / BLOCK;
    tree_mlp_kernel<<<grid, BLOCK, 0, stream>>>(
        x, W1, b1, W2, b2, W3, b3, leaf_best, subset, (float*)d_out, N);
}